// Round 10
// baseline (224.087 us; speedup 1.0000x reference)
//
#include <hip/hip_runtime.h>
#include <hip/hip_fp16.h>

using half8  = __attribute__((ext_vector_type(8))) _Float16;
using half4  = __attribute__((ext_vector_type(4))) _Float16;
using f32x4  = __attribute__((ext_vector_type(4))) float;

#define GROUPS      3333
#define BINNER_OUT  9999
#define BATCH       256
#define ROWS        512          // 2 spectra x 256
#define PEAKS       512
#define K1          9999
#define K1P         10048        // padded to mult of 64 (157*64)
#define NP          1024         // hidden 1000 padded
#define NOP         512          // out 500 padded

// ---- async global->LDS, 16B per lane (dest = uniform base + lane*16) ------
__device__ __forceinline__ void gl_lds16(const void* g, void* l) {
  __builtin_amdgcn_global_load_lds(
      (const __attribute__((address_space(1))) void*)g,
      (__attribute__((address_space(3))) void*)l, 16, 0, 0);
}

// ---- native LDS fp32 atomic add (relaxed, workgroup scope -> ds_add_f32) --
__device__ __forceinline__ void hs_add(float* p, float v) {
  __hip_atomic_fetch_add(p, v, __ATOMIC_RELAXED, __HIP_MEMORY_SCOPE_WORKGROUP);
}

__global__ void init_flags(unsigned* f) {
  if (threadIdx.x < 32) f[threadIdx.x] = 0u;
}

// ---- mega: bin(row) + transp share + L1 GEMM tile, one kernel -------------
// Grid = 512 blocks exactly (2/CU by 72KB LDS -> all co-resident).
// flags[0..7]  = hband: # of rows written per 64-row band
// flags[8..23] = wtile: # of W1 k-groups done per W1t 64-row n-tile
__global__ __launch_bounds__(256, 2) void mega(
    const float* __restrict__ mz1, const float* __restrict__ it1,
    const float* __restrict__ mz2, const float* __restrict__ it2,
    const float* __restrict__ Wg,  const float* __restrict__ bg,
    _Float16* __restrict__ h16,
    const float* __restrict__ W1, _Float16* __restrict__ W1t,
    const float* __restrict__ W2, _Float16* __restrict__ W2t,
    const float* __restrict__ W3, _Float16* __restrict__ W3t,
    const float* __restrict__ Wo, _Float16* __restrict__ Wot,
    float* __restrict__ part, unsigned* __restrict__ flags) {
  __shared__ __align__(16) char smem[73728];        // union of all phases
  const int t = threadIdx.x;
  const int bid = blockIdx.x;

  // ================= phase A: bin row `bid` =================
  {
    float* hs = (float*)smem;                       // 10048 floats = 40.2 KB
    const int s = bid >> 8, b = bid & 255;
    for (int k = t * 4; k < K1P; k += 1024)
      *(f32x4*)&hs[k] = (f32x4){0.f, 0.f, 0.f, 0.f};
    __syncthreads();

    const float* mz = (s ? mz2 : mz1) + (size_t)b * PEAKS;
    const float* it = (s ? it2 : it1) + (size_t)b * PEAKS;
    float m[2], v[2], w[2][3]; int c0[2]; bool keep[2];
#pragma unroll
    for (int q = 0; q < 2; ++q) { m[q] = mz[t + q * 256]; v[q] = it[t + q * 256]; }
#pragma unroll
    for (int q = 0; q < 2; ++q) {
      bool val = (m[q] >= 0.0f && m[q] < 1000.0f);
      int bin = val ? (int)floorf(m[q] / 0.01f) : 0;  // IEEE div+floor = jnp
      bin = bin < 0 ? 0 : (bin > 99999 ? 99999 : bin);
      keep[q] = val && (bin < GROUPS * 30);       // ref drops bins 99990..99999
      int binL = bin < GROUPS * 30 ? bin : GROUPS * 30 - 1;
      const float* wp = Wg + (size_t)binL * 3;    // Wg[g][i][o] flat
      w[q][0] = wp[0]; w[q][1] = wp[1]; w[q][2] = wp[2];
      c0[q] = (bin / 30) * 3;
    }
#pragma unroll
    for (int q = 0; q < 2; ++q)
      if (keep[q]) {
#pragma unroll
        for (int o = 0; o < 3; ++o) hs_add(&hs[c0[q] + o], v[q] * w[q][o]);
      }
    __syncthreads();

    _Float16* dst = h16 + (size_t)bid * K1P;
    for (int k0 = t * 8; k0 < K1P; k0 += 2048) {
      half8 vv;
#pragma unroll
      for (int j = 0; j < 8; ++j) {
        int c = k0 + j;
        float x = hs[c] + (c < BINNER_OUT ? bg[c] : 0.f);
        vv[j] = (_Float16)x;
      }
      *(half8*)(dst + k0) = vv;
    }
  }
  __syncthreads();                                  // row stores drained
  if (t == 0) {
    __builtin_amdgcn_fence(__ATOMIC_RELEASE, "agent");
    __hip_atomic_fetch_add(&flags[bid >> 6], 1u, __ATOMIC_ACQ_REL,
                           __HIP_MEMORY_SCOPE_AGENT);
  }

  // ================= phase B: transpose groups (<=2) =================
  // group g<640: W1 (kgroup g%40, ntile g/40); 640..704 W2; ..768 W3; ..800 Wo
  for (int g = bid; g < 800; g += 512) {
    float (*tile)[66] = (float(*)[66])smem;         // 16.9 KB
    const float* W; _Float16* outp; int K, N, Kpad, kg, in, ktiles;
    if (g < 640)      { W = W1; outp = W1t; K = K1;   N = 1000; Kpad = K1P;
                        ktiles = 157; kg = g % 40; in = g / 40; }
    else if (g < 704) { int lb = g - 640; W = W2; outp = W2t; K = 1000; N = 1000;
                        Kpad = NP; ktiles = 16; kg = lb & 3; in = lb >> 2; }
    else if (g < 768) { int lb = g - 704; W = W3; outp = W3t; K = 1000; N = 1000;
                        Kpad = NP; ktiles = 16; kg = lb & 3; in = lb >> 2; }
    else              { int lb = g - 768; W = Wo; outp = Wot; K = 1000; N = 500;
                        Kpad = NP; ktiles = 16; kg = lb & 3; in = lb >> 2; }
    const int ntile = min(4, ktiles - kg * 4);
    const int k0base = kg * 256, n0 = in * 64;
    const int r = t >> 2, cc = (t & 3) * 16;

    f32x4 cur[4], nxt[4];
    auto LOAD = [&](int i, f32x4* d) {
      int k = k0base + i * 64 + r;
#pragma unroll
      for (int j = 0; j < 4; ++j) {
        int n = n0 + cc + j * 4;
        f32x4 v = (f32x4){0.f, 0.f, 0.f, 0.f};
        if (k < K && n < N) v = *(const f32x4*)(W + (size_t)k * N + n);
        d[j] = v;
      }
    };
    LOAD(0, cur);
    for (int i = 0; i < ntile; ++i) {
      __syncthreads();                              // tile LDS free
#pragma unroll
      for (int j = 0; j < 4; ++j) {
        tile[r][cc + j * 4 + 0] = cur[j][0];
        tile[r][cc + j * 4 + 1] = cur[j][1];
        tile[r][cc + j * 4 + 2] = cur[j][2];
        tile[r][cc + j * 4 + 3] = cur[j][3];
      }
      __syncthreads();
      if (i + 1 < ntile) LOAD(i + 1, nxt);
      const int k0 = k0base + i * 64;
#pragma unroll
      for (int h = 0; h < 2; ++h) {
        half8 v;
#pragma unroll
        for (int e = 0; e < 8; ++e) v[e] = (_Float16)tile[cc + h * 8 + e][r];
        *(half8*)(outp + (size_t)(n0 + r) * Kpad + k0 + cc + h * 8) = v;
      }
#pragma unroll
      for (int j = 0; j < 4; ++j) cur[j] = nxt[j];
    }
    __syncthreads();                                // group stores drained
    if (t == 0 && g < 640) {
      __builtin_amdgcn_fence(__ATOMIC_RELEASE, "agent");
      __hip_atomic_fetch_add(&flags[8 + g / 40], 1u, __ATOMIC_ACQ_REL,
                             __HIP_MEMORY_SCOPE_AGENT);
    }
  }

  // ================= phase C: L1 GEMM tile =================
  // 512 blocks = 8x8x8 XCD-swizzled (bx n-tile, by m-tile, bz k-slice)
  int xcd = bid & 7, i2 = bid >> 3;
  const int bz = i2 >> 3;
  int j2 = i2 & 7;
  const int bx = (xcd & 3) * 2 + (j2 & 1);
  const int by = (xcd >> 2) * 4 + (j2 >> 1);

  if (t == 0) {                                     // wait for MY producers
    while (__hip_atomic_load(&flags[by], __ATOMIC_ACQUIRE,
                             __HIP_MEMORY_SCOPE_AGENT) < 64u ||
           __hip_atomic_load(&flags[8 + 2 * bx], __ATOMIC_ACQUIRE,
                             __HIP_MEMORY_SCOPE_AGENT) < 40u ||
           __hip_atomic_load(&flags[8 + 2 * bx + 1], __ATOMIC_ACQUIRE,
                             __HIP_MEMORY_SCOPE_AGENT) < 40u)
      __builtin_amdgcn_s_sleep(2);
  }
  __syncthreads();
  __builtin_amdgcn_fence(__ATOMIC_ACQUIRE, "agent");  // L1 invalidate

  {
    _Float16* As = (_Float16*)smem;                 // 3 x 64x64  = 24 KB
    _Float16* Bs = (_Float16*)(smem + 24576);       // 3 x 128x64 = 48 KB
    const int lane = t & 63, wid = t >> 6;
    const int m0 = by * 64, n0 = bx * 128;
    const int s0 = bz * 20;
    const int s1 = min(s0 + 20, 157);
    const int wr = wid >> 1, wc = wid & 1;
    const int r16 = lane & 15, kh = lane >> 4;
    const int lr  = lane >> 3;
    const int lkc = ((lane & 7) ^ lr) * 8;
    const _Float16* AgL = h16 + (size_t)(m0 + wid * 16 + lr) * K1P + lkc;
    const _Float16* BgL = W1t + (size_t)(n0 + wid * 32 + lr) * K1P + lkc;

    f32x4 acc[2][4] = {};
    auto STAGE = [&](int s, int buf) {
      const size_t ko = (size_t)s * 64;
      _Float16* ab = As + buf * 4096 + wid * 1024;
      _Float16* bb = Bs + buf * 8192 + wid * 2048;
      gl_lds16(AgL + ko,                    ab);
      gl_lds16(AgL + ko + (size_t) 8 * K1P, ab + 512);
      gl_lds16(BgL + ko,                    bb);
      gl_lds16(BgL + ko + (size_t) 8 * K1P, bb + 512);
      gl_lds16(BgL + ko + (size_t)16 * K1P, bb + 1024);
      gl_lds16(BgL + ko + (size_t)24 * K1P, bb + 1536);
    };
    STAGE(s0, 0);
    STAGE(s0 + 1, 1);

    int cur = 0;
    for (int s = s0; s < s1; ++s) {
      __builtin_amdgcn_s_barrier();
      const bool more2 = (s + 2 < s1), more1 = (s + 1 < s1);
      if (more2) STAGE(s + 2, cur == 0 ? 2 : (cur == 1 ? 0 : 1));
      if (more2)      asm volatile("s_waitcnt vmcnt(12)" ::: "memory");
      else if (more1) asm volatile("s_waitcnt vmcnt(6)"  ::: "memory");
      else            asm volatile("s_waitcnt vmcnt(0)"  ::: "memory");
      __builtin_amdgcn_s_barrier();

      const char* Ab = (const char*)(As + cur * 4096);
      const char* Bb = (const char*)(Bs + cur * 8192);
      half8 af[2][2], bf[4][2];
#pragma unroll
      for (int kc = 0; kc < 2; ++kc) {
#pragma unroll
        for (int mi = 0; mi < 2; ++mi) {
          int row = wr * 32 + mi * 16 + r16;
          af[mi][kc] = *(const half8*)(Ab + row * 128 +
                       (((kc << 6) + (kh << 4)) ^ ((row & 7) << 4)));
        }
#pragma unroll
        for (int ni = 0; ni < 4; ++ni) {
          int row = wc * 64 + ni * 16 + r16;
          bf[ni][kc] = *(const half8*)(Bb + row * 128 +
                       (((kc << 6) + (kh << 4)) ^ ((row & 7) << 4)));
        }
      }
#pragma unroll
      for (int kc = 0; kc < 2; ++kc)
#pragma unroll
        for (int mi = 0; mi < 2; ++mi)
#pragma unroll
          for (int ni = 0; ni < 4; ++ni)
            acc[mi][ni] = __builtin_amdgcn_mfma_f32_16x16x32_f16(
                af[mi][kc], bf[ni][kc], acc[mi][ni], 0, 0, 0);
      cur = cur == 2 ? 0 : cur + 1;
    }

    float* P = part + (size_t)bz * ROWS * NP;
#pragma unroll
    for (int mi = 0; mi < 2; ++mi)
#pragma unroll
      for (int ni = 0; ni < 4; ++ni) {
        int row = m0 + wr * 32 + mi * 16 + kh * 4;
        int col = n0 + wc * 64 + ni * 16 + r16;
#pragma unroll
        for (int rr = 0; rr < 4; ++rr)
          P[(size_t)(row + rr) * NP + col] = acc[mi][ni][rr];
      }
  }
}

// ---- split-K fp16 MFMA GEMM (L2/L3/Lo), 3-deep counted-vmcnt pipeline -----
template <bool SWZ>
__global__ __launch_bounds__(256) void gemm_sk(
    const _Float16* __restrict__ A, int lda,
    const _Float16* __restrict__ Bt, int ldb,
    float* __restrict__ part, int M, int Npad, int ksteps_total, int kspc) {
  __shared__ __align__(16) _Float16 As[3 * 4096];
  __shared__ __align__(16) _Float16 Bs[3 * 8192];

  int bx, by, bz;
  if (SWZ) {
    int bid = blockIdx.x;
    int xcd = bid & 7, i = bid >> 3;
    bz = i >> 3;
    int j = i & 7;
    bx = (xcd & 3) * 2 + (j & 1);
    by = (xcd >> 2) * 4 + (j >> 1);
  } else {
    bx = blockIdx.x; by = blockIdx.y; bz = blockIdx.z;
  }

  const int t = threadIdx.x, lane = t & 63, wid = t >> 6;
  const int m0 = by * 64, n0 = bx * 128;
  const int s0 = bz * kspc;
  const int s1 = min(s0 + kspc, ksteps_total);
  const int wr = wid >> 1, wc = wid & 1;
  const int r16 = lane & 15, kh = lane >> 4;
  const int lr  = lane >> 3;
  const int lkc = ((lane & 7) ^ lr) * 8;
  const _Float16* AgL = A  + (size_t)(m0 + wid * 16 + lr) * lda + lkc;
  const _Float16* BgL = Bt + (size_t)(n0 + wid * 32 + lr) * ldb + lkc;

  f32x4 acc[2][4] = {};
  auto STAGE = [&](int s, int buf) {
    const size_t ko = (size_t)s * 64;
    _Float16* ab = As + buf * 4096 + wid * 1024;
    _Float16* bb = Bs + buf * 8192 + wid * 2048;
    gl_lds16(AgL + ko,                     ab);
    gl_lds16(AgL + ko + (size_t) 8 * lda,  ab + 512);
    gl_lds16(BgL + ko,                     bb);
    gl_lds16(BgL + ko + (size_t) 8 * ldb,  bb + 512);
    gl_lds16(BgL + ko + (size_t)16 * ldb,  bb + 1024);
    gl_lds16(BgL + ko + (size_t)24 * ldb,  bb + 1536);
  };

  if (s0 < s1)     STAGE(s0, 0);
  if (s0 + 1 < s1) STAGE(s0 + 1, 1);

  int cur = 0;
  for (int s = s0; s < s1; ++s) {
    __builtin_amdgcn_s_barrier();
    const bool more2 = (s + 2 < s1), more1 = (s + 1 < s1);
    if (more2) STAGE(s + 2, cur == 0 ? 2 : (cur == 1 ? 0 : 1));
    if (more2)      asm volatile("s_waitcnt vmcnt(12)" ::: "memory");
    else if (more1) asm volatile("s_waitcnt vmcnt(6)"  ::: "memory");
    else            asm volatile("s_waitcnt vmcnt(0)"  ::: "memory");
    __builtin_amdgcn_s_barrier();

    const char* Ab = (const char*)(As + cur * 4096);
    const char* Bb = (const char*)(Bs + cur * 8192);
    half8 af[2][2], bf[4][2];
#pragma unroll
    for (int kc = 0; kc < 2; ++kc) {
#pragma unroll
      for (int mi = 0; mi < 2; ++mi) {
        int row = wr * 32 + mi * 16 + r16;
        af[mi][kc] = *(const half8*)(Ab + row * 128 +
                     (((kc << 6) + (kh << 4)) ^ ((row & 7) << 4)));
      }
#pragma unroll
      for (int ni = 0; ni < 4; ++ni) {
        int row = wc * 64 + ni * 16 + r16;
        bf[ni][kc] = *(const half8*)(Bb + row * 128 +
                     (((kc << 6) + (kh << 4)) ^ ((row & 7) << 4)));
      }
    }
#pragma unroll
    for (int kc = 0; kc < 2; ++kc)
#pragma unroll
      for (int mi = 0; mi < 2; ++mi)
#pragma unroll
        for (int ni = 0; ni < 4; ++ni)
          acc[mi][ni] = __builtin_amdgcn_mfma_f32_16x16x32_f16(
              af[mi][kc], bf[ni][kc], acc[mi][ni], 0, 0, 0);
    cur = cur == 2 ? 0 : cur + 1;
  }

  float* P = part + (size_t)bz * M * Npad;
#pragma unroll
  for (int mi = 0; mi < 2; ++mi)
#pragma unroll
    for (int ni = 0; ni < 4; ++ni) {
      int row = m0 + wr * 32 + mi * 16 + kh * 4;
      int col = n0 + wc * 64 + ni * 16 + r16;
#pragma unroll
      for (int rr = 0; rr < 4; ++rr)
        P[(size_t)(row + rr) * Npad + col] = acc[mi][ni][rr];
    }
}

// ---- combine split-K partials + bias + relu, emit fp16 (vectorized) -------
__global__ void combine_sk(const float* __restrict__ part, int SK, int M, int Npad,
                           const float* __restrict__ bias, int Nreal,
                           _Float16* __restrict__ o16) {
  int i4 = (blockIdx.x * 256 + threadIdx.x) * 4;
  int total = M * Npad;
  if (i4 >= total) return;
  f32x4 s = (f32x4){0.f, 0.f, 0.f, 0.f};
  for (int zz = 0; zz < SK; ++zz)
    s += *(const f32x4*)&part[(size_t)zz * total + i4];
  int n = i4 & (Npad - 1);
  half4 v;
#pragma unroll
  for (int e = 0; e < 4; ++e) {
    float x = s[e] + ((n + e) < Nreal ? bias[n + e] : 0.f);
    v[e] = (_Float16)fmaxf(x, 0.f);
  }
  *(half4*)(o16 + i4) = v;
}

// ---- final combine (split-K + bias, no relu) fused with cosine ------------
__global__ void combine_cos(const float* __restrict__ part,
                            const float* __restrict__ bo,
                            float* __restrict__ out) {
  const int b = blockIdx.x, t = threadIdx.x;
  float d = 0.f, s1 = 0.f, s2 = 0.f;
  for (int c = t; c < NOP; c += 256) {
    float e1 = 0.f, e2 = 0.f;
#pragma unroll
    for (int z = 0; z < 8; ++z) {
      e1 += part[((size_t)z * ROWS + b) * NOP + c];
      e2 += part[((size_t)z * ROWS + b + BATCH) * NOP + c];
    }
    if (c < 500) { float bb = bo[c]; e1 += bb; e2 += bb; }
    d += e1 * e2; s1 += e1 * e1; s2 += e2 * e2;
  }
  for (int off = 32; off > 0; off >>= 1) {
    d  += __shfl_down(d, off, 64);
    s1 += __shfl_down(s1, off, 64);
    s2 += __shfl_down(s2, off, 64);
  }
  __shared__ float rd[4], r1[4], r2[4];
  int wd = t >> 6, lane = t & 63;
  if (lane == 0) { rd[wd] = d; r1[wd] = s1; r2[wd] = s2; }
  __syncthreads();
  if (t == 0) {
    float D  = rd[0] + rd[1] + rd[2] + rd[3];
    float S1 = r1[0] + r1[1] + r1[2] + r1[3];
    float S2 = r2[0] + r2[1] + r2[2] + r2[3];
    float n1 = fmaxf(sqrtf(S1), 1e-6f);
    float n2 = fmaxf(sqrtf(S2), 1e-6f);
    out[b] = D / (n1 * n2);
  }
}

extern "C" void kernel_launch(void* const* d_in, const int* in_sizes, int n_in,
                              void* d_out, int out_size, void* d_ws, size_t ws_size,
                              hipStream_t stream) {
  const float* mz1 = (const float*)d_in[0];
  const float* it1 = (const float*)d_in[1];
  const float* mz2 = (const float*)d_in[2];
  const float* it2 = (const float*)d_in[3];
  const float* Wg  = (const float*)d_in[4];
  const float* bg  = (const float*)d_in[5];
  const float* W1  = (const float*)d_in[6];
  const float* b1  = (const float*)d_in[7];
  const float* W2  = (const float*)d_in[8];
  const float* b2  = (const float*)d_in[9];
  const float* W3  = (const float*)d_in[10];
  const float* b3  = (const float*)d_in[11];
  const float* Wo  = (const float*)d_in[12];
  const float* bo  = (const float*)d_in[13];
  float* out = (float*)d_out;

  char* ws = (char*)d_ws;
  size_t off = 0;
  auto take = [&](size_t bytes) {
    size_t o = off; off += (bytes + 255) & ~(size_t)255; return o;
  };
  float*    part  = (float*)   (ws + take((size_t)8 * ROWS * NP * 4)); // 16MB
  _Float16* h16   = (_Float16*)(ws + take((size_t)ROWS * K1P * 2));
  _Float16* W1t   = (_Float16*)(ws + take((size_t)NP * K1P * 2));
  _Float16* W2t   = (_Float16*)(ws + take((size_t)NP * NP * 2));
  _Float16* W3t   = (_Float16*)(ws + take((size_t)NP * NP * 2));
  _Float16* Wot   = (_Float16*)(ws + take((size_t)NOP * NP * 2));
  _Float16* y1    = (_Float16*)(ws + take((size_t)ROWS * NP * 2));
  _Float16* y2    = (_Float16*)(ws + take((size_t)ROWS * NP * 2));
  _Float16* y3    = (_Float16*)(ws + take((size_t)ROWS * NP * 2));
  unsigned* flags = (unsigned*)(ws + take(128));

  // 1) zero producer-consumer flags (inside graph; deterministic per replay)
  init_flags<<<1, 64, 0, stream>>>(flags);

  // 2) bin + transposes + L1 GEMM fused, fine-grained flag sync
  mega<<<512, 256, 0, stream>>>(mz1, it1, mz2, it2, Wg, bg, h16,
                                W1, W1t, W2, W2t, W3, W3t, Wo, Wot,
                                part, flags);
  combine_sk<<<(ROWS * NP) / 1024, 256, 0, stream>>>(part, 8, ROWS, NP, b1, 1000, y1);

  // 3) L2/L3/Lo GEMMs + combines
  gemm_sk<true><<<512, 256, 0, stream>>>(
      y1, NP, W2t, NP, part, ROWS, NP, NP / 64, 2);
  combine_sk<<<(ROWS * NP) / 1024, 256, 0, stream>>>(part, 8, ROWS, NP, b2, 1000, y2);

  gemm_sk<true><<<512, 256, 0, stream>>>(
      y2, NP, W3t, NP, part, ROWS, NP, NP / 64, 2);
  combine_sk<<<(ROWS * NP) / 1024, 256, 0, stream>>>(part, 8, ROWS, NP, b3, 1000, y3);

  gemm_sk<false><<<dim3(NOP / 128, ROWS / 64, 8), 256, 0, stream>>>(
      y3, NP, Wot, NP, part, ROWS, NOP, NP / 64, 2);

  // 4) final combine + cosine
  combine_cos<<<BATCH, 256, 0, stream>>>(part, bo, out);
}

// Round 11
// 89.263 us; speedup vs baseline: 2.5104x; 2.5104x over previous
//
#include <hip/hip_runtime.h>
#include <hip/hip_fp16.h>

using half8  = __attribute__((ext_vector_type(8))) _Float16;
using half4  = __attribute__((ext_vector_type(4))) _Float16;
using f32x4  = __attribute__((ext_vector_type(4))) float;

#define GROUPS      3333
#define BINNER_OUT  9999
#define BATCH       256
#define ROWS        512          // 2 spectra x 256
#define PEAKS       512
#define K1          9999
#define K1P         10048        // padded to mult of 64 (157*64)
#define NP          1024         // hidden 1000 padded
#define NOP         512          // out 500 padded
#define HALFK       5024         // K1P/2, per-bin-block column range

// ---- async global->LDS, 16B per lane (dest = uniform base + lane*16) ------
__device__ __forceinline__ void gl_lds16(const void* g, void* l) {
  __builtin_amdgcn_global_load_lds(
      (const __attribute__((address_space(1))) void*)g,
      (__attribute__((address_space(3))) void*)l, 16, 0, 0);
}

// ---- native LDS fp32 atomic add (relaxed, workgroup scope -> ds_add_f32) --
__device__ __forceinline__ void hs_add(float* p, float v) {
  __hip_atomic_fetch_add(p, v, __ATOMIC_RELAXED, __HIP_MEMORY_SCOPE_WORKGROUP);
}

// ---- prep4: binning (1024 blocks, half-row each) + transposes (800) -------
__global__ __launch_bounds__(256) void prep4(
    const float* __restrict__ mz1, const float* __restrict__ it1,
    const float* __restrict__ mz2, const float* __restrict__ it2,
    const float* __restrict__ Wg,  const float* __restrict__ bg,
    _Float16* __restrict__ h16,
    const float* __restrict__ W1, _Float16* __restrict__ W1t,
    const float* __restrict__ W2, _Float16* __restrict__ W2t,
    const float* __restrict__ W3, _Float16* __restrict__ W3t,
    const float* __restrict__ Wo, _Float16* __restrict__ Wot) {
  __shared__ __align__(16) char smem[HALFK * 4];    // 20096 B
  const int t = threadIdx.x;
  const int blk = blockIdx.x;

  if (blk < 1024) {
    // ---------------- binning + grouped linear (half row) ----------------
    float* hs = (float*)smem;                       // 5024 floats
    const int row = blk >> 1, half = blk & 1;
    const int base = half * HALFK;
    const int s = row >> 8, b = row & 255;

    for (int k = t * 4; k < HALFK; k += 1024)
      *(f32x4*)&hs[k] = (f32x4){0.f, 0.f, 0.f, 0.f};
    __syncthreads();

    const float* mz = (s ? mz2 : mz1) + (size_t)b * PEAKS;
    const float* it = (s ? it2 : it1) + (size_t)b * PEAKS;

    float m[2], v[2], w[2][3]; int c0[2]; bool keep[2];
#pragma unroll
    for (int q = 0; q < 2; ++q) { m[q] = mz[t + q * 256]; v[q] = it[t + q * 256]; }
#pragma unroll
    for (int q = 0; q < 2; ++q) {
      bool val = (m[q] >= 0.0f && m[q] < 1000.0f);
      int bin = val ? (int)floorf(m[q] / 0.01f) : 0;  // IEEE div+floor = jnp
      bin = bin < 0 ? 0 : (bin > 99999 ? 99999 : bin);
      keep[q] = val && (bin < GROUPS * 30);       // ref drops bins 99990..99999
      int binL = bin < GROUPS * 30 ? bin : GROUPS * 30 - 1;  // safe gather idx
      const float* wp = Wg + (size_t)binL * 3;    // Wg[g][i][o] flat
      w[q][0] = wp[0]; w[q][1] = wp[1]; w[q][2] = wp[2];
      c0[q] = (bin / 30) * 3;
    }
#pragma unroll
    for (int q = 0; q < 2; ++q)
      if (keep[q]) {
#pragma unroll
        for (int o = 0; o < 3; ++o) {
          int c = c0[q] + o;
          if (c >= base && c < base + HALFK)
            hs_add(&hs[c - base], v[q] * w[q][o]);
        }
      }
    __syncthreads();

    _Float16* dst = h16 + (size_t)row * K1P + base;
    for (int k0 = t * 8; k0 < HALFK; k0 += 2048) {
      half8 vv;
#pragma unroll
      for (int j = 0; j < 8; ++j) {
        int c = base + k0 + j;
        float x = hs[k0 + j] + (c < BINNER_OUT ? bg[c] : 0.f);
        vv[j] = (_Float16)x;
      }
      *(half8*)(dst + k0) = vv;
    }
  } else {
    // ------- weight transpose+convert, 4 x (64x64) tiles per block -------
    float (*tile)[66] = (float(*)[66])smem;         // 16896 B
    int bid = blk - 1024;
    const float* W; _Float16* outp; int K, N, Kpad, g, in, ktiles;
    if (bid < 640)       { W = W1; outp = W1t; K = K1;   N = 1000; Kpad = K1P;
                           ktiles = 157; g = bid % 40; in = bid / 40; }
    else if (bid < 704)  { bid -= 640; W = W2; outp = W2t; K = 1000; N = 1000;
                           Kpad = NP; ktiles = 16; g = bid & 3; in = bid >> 2; }
    else if (bid < 768)  { bid -= 704; W = W3; outp = W3t; K = 1000; N = 1000;
                           Kpad = NP; ktiles = 16; g = bid & 3; in = bid >> 2; }
    else                 { bid -= 768; W = Wo; outp = Wot; K = 1000; N = 500;
                           Kpad = NP; ktiles = 16; g = bid & 3; in = bid >> 2; }
    const int ntile = min(4, ktiles - g * 4);
    const int k0base = g * 256, n0 = in * 64;
    const int r = t >> 2, cc = (t & 3) * 16;

    f32x4 cur[4], nxt[4];
    auto LOAD = [&](int i, f32x4* dst) {
      int k = k0base + i * 64 + r;
#pragma unroll
      for (int j = 0; j < 4; ++j) {
        int n = n0 + cc + j * 4;
        f32x4 v = (f32x4){0.f, 0.f, 0.f, 0.f};
        if (k < K && n < N)                 // N % 4 == 0: whole-chunk validity
          v = *(const f32x4*)(W + (size_t)k * N + n);
        dst[j] = v;
      }
    };

    LOAD(0, cur);
    for (int i = 0; i < ntile; ++i) {
      if (i) __syncthreads();
#pragma unroll
      for (int j = 0; j < 4; ++j) {
        tile[r][cc + j * 4 + 0] = cur[j][0];
        tile[r][cc + j * 4 + 1] = cur[j][1];
        tile[r][cc + j * 4 + 2] = cur[j][2];
        tile[r][cc + j * 4 + 3] = cur[j][3];
      }
      __syncthreads();
      if (i + 1 < ntile) LOAD(i + 1, nxt);
      const int k0 = k0base + i * 64;
#pragma unroll
      for (int h = 0; h < 2; ++h) {
        half8 v;
#pragma unroll
        for (int e = 0; e < 8; ++e) v[e] = (_Float16)tile[cc + h * 8 + e][r];
        *(half8*)(outp + (size_t)(n0 + r) * Kpad + k0 + cc + h * 8) = v;
      }
#pragma unroll
      for (int j = 0; j < 4; ++j) cur[j] = nxt[j];
    }
  }
}

// ---- split-K fp16 MFMA GEMM (L1 only), 3-deep counted-vmcnt pipeline ------
template <bool SWZ>
__global__ __launch_bounds__(256) void gemm_sk(
    const _Float16* __restrict__ A, int lda,
    const _Float16* __restrict__ Bt, int ldb,
    float* __restrict__ part, int M, int Npad, int ksteps_total, int kspc) {
  __shared__ __align__(16) _Float16 As[3 * 4096];   // 3 x 64x64  = 24 KB
  __shared__ __align__(16) _Float16 Bs[3 * 8192];   // 3 x 128x64 = 48 KB

  int bx, by, bz;
  if (SWZ) {   // 512 blocks = 8x8x8; each XCD owns a 2(bx) x 4(by) region
    int bid = blockIdx.x;
    int xcd = bid & 7, i = bid >> 3;
    bz = i >> 3;
    int j = i & 7;
    bx = (xcd & 3) * 2 + (j & 1);
    by = (xcd >> 2) * 4 + (j >> 1);
  } else {
    bx = blockIdx.x; by = blockIdx.y; bz = blockIdx.z;
  }

  const int t = threadIdx.x, lane = t & 63, wid = t >> 6;
  const int m0 = by * 64, n0 = bx * 128;
  const int s0 = bz * kspc;
  const int s1 = min(s0 + kspc, ksteps_total);

  const int wr = wid >> 1, wc = wid & 1;            // 2x2 waves, 32x64 each
  const int r16 = lane & 15, kh = lane >> 4;
  const int lr  = lane >> 3;
  const int lkc = ((lane & 7) ^ lr) * 8;
  const _Float16* AgL = A  + (size_t)(m0 + wid * 16 + lr) * lda + lkc;
  const _Float16* BgL = Bt + (size_t)(n0 + wid * 32 + lr) * ldb + lkc;

  f32x4 acc[2][4] = {};
  auto STAGE = [&](int s, int buf) {
    const size_t ko = (size_t)s * 64;
    _Float16* ab = As + buf * 4096 + wid * 1024;
    _Float16* bb = Bs + buf * 8192 + wid * 2048;
    gl_lds16(AgL + ko,                     ab);
    gl_lds16(AgL + ko + (size_t) 8 * lda,  ab + 512);
    gl_lds16(BgL + ko,                     bb);
    gl_lds16(BgL + ko + (size_t) 8 * ldb,  bb + 512);
    gl_lds16(BgL + ko + (size_t)16 * ldb,  bb + 1024);
    gl_lds16(BgL + ko + (size_t)24 * ldb,  bb + 1536);
  };

  if (s0 < s1)     STAGE(s0, 0);
  if (s0 + 1 < s1) STAGE(s0 + 1, 1);

  int cur = 0;
  for (int s = s0; s < s1; ++s) {
    __builtin_amdgcn_s_barrier();
    const bool more2 = (s + 2 < s1), more1 = (s + 1 < s1);
    if (more2) STAGE(s + 2, cur == 0 ? 2 : (cur == 1 ? 0 : 1));
    if (more2)      asm volatile("s_waitcnt vmcnt(12)" ::: "memory");
    else if (more1) asm volatile("s_waitcnt vmcnt(6)"  ::: "memory");
    else            asm volatile("s_waitcnt vmcnt(0)"  ::: "memory");
    __builtin_amdgcn_s_barrier();

    const char* Ab = (const char*)(As + cur * 4096);
    const char* Bb = (const char*)(Bs + cur * 8192);
    half8 af[2][2], bf[4][2];
#pragma unroll
    for (int kc = 0; kc < 2; ++kc) {
#pragma unroll
      for (int mi = 0; mi < 2; ++mi) {
        int row = wr * 32 + mi * 16 + r16;
        af[mi][kc] = *(const half8*)(Ab + row * 128 +
                     (((kc << 6) + (kh << 4)) ^ ((row & 7) << 4)));
      }
#pragma unroll
      for (int ni = 0; ni < 4; ++ni) {
        int row = wc * 64 + ni * 16 + r16;
        bf[ni][kc] = *(const half8*)(Bb + row * 128 +
                     (((kc << 6) + (kh << 4)) ^ ((row & 7) << 4)));
      }
    }
#pragma unroll
    for (int kc = 0; kc < 2; ++kc)
#pragma unroll
      for (int mi = 0; mi < 2; ++mi)
#pragma unroll
        for (int ni = 0; ni < 4; ++ni)
          acc[mi][ni] = __builtin_amdgcn_mfma_f32_16x16x32_f16(
              af[mi][kc], bf[ni][kc], acc[mi][ni], 0, 0, 0);
    cur = cur == 2 ? 0 : cur + 1;
  }

  float* P = part + (size_t)bz * M * Npad;
#pragma unroll
  for (int mi = 0; mi < 2; ++mi)
#pragma unroll
    for (int ni = 0; ni < 4; ++ni) {
      int row = m0 + wr * 32 + mi * 16 + kh * 4;    // C/D: row=(l>>4)*4+rr
      int col = n0 + wc * 64 + ni * 16 + r16;       //      col=l&15
#pragma unroll
      for (int rr = 0; rr < 4; ++rr)
        P[(size_t)(row + rr) * Npad + col] = acc[mi][ni][rr];
    }
}

// ---- full-K fp16 MFMA GEMM (L2/L3/Lo): 64x64 tile, fused bias(+relu) ------
// A [512][NP] fp16, Bt [Npad][NP] fp16 k-major; K = NP (16 steps of 64).
// Epilogue: + bias (col<Nreal), optional relu; emit fp16 (o16) or fp32 (o32).
template <int RELU>
__global__ __launch_bounds__(256) void gemm_full(
    const _Float16* __restrict__ A,
    const _Float16* __restrict__ Bt,
    const float* __restrict__ bias, int Nreal, int Npad,
    _Float16* __restrict__ o16, float* __restrict__ o32) {
  __shared__ __align__(16) _Float16 As[3 * 4096];   // 3 x 64x64 = 24 KB
  __shared__ __align__(16) _Float16 Bs[3 * 4096];   // 3 x 64x64 = 24 KB

  const int bx = blockIdx.x, by = blockIdx.y;
  const int t = threadIdx.x, lane = t & 63, wid = t >> 6;
  const int m0 = by * 64, n0 = bx * 64;
  const int wr = wid >> 1, wc = wid & 1;            // 2x2 waves, 32x32 each
  const int r16 = lane & 15, kh = lane >> 4;
  const int lr  = lane >> 3;
  const int lkc = ((lane & 7) ^ lr) * 8;
  const _Float16* AgL = A  + (size_t)(m0 + wid * 16 + lr) * NP + lkc;
  const _Float16* BgL = Bt + (size_t)(n0 + wid * 16 + lr) * NP + lkc;

  f32x4 acc[2][2] = {};
  auto STAGE = [&](int s, int buf) {                // 4 VMEM insts / thread
    const size_t ko = (size_t)s * 64;
    _Float16* ab = As + buf * 4096 + wid * 1024;
    _Float16* bb = Bs + buf * 4096 + wid * 1024;
    gl_lds16(AgL + ko,                    ab);
    gl_lds16(AgL + ko + (size_t)8 * NP,   ab + 512);
    gl_lds16(BgL + ko,                    bb);
    gl_lds16(BgL + ko + (size_t)8 * NP,   bb + 512);
  };

  STAGE(0, 0);
  STAGE(1, 1);

  int cur = 0;
  for (int s = 0; s < 16; ++s) {
    __builtin_amdgcn_s_barrier();
    const bool more2 = (s + 2 < 16), more1 = (s + 1 < 16);
    if (more2) STAGE(s + 2, cur == 0 ? 2 : (cur == 1 ? 0 : 1));
    if (more2)      asm volatile("s_waitcnt vmcnt(8)" ::: "memory");
    else if (more1) asm volatile("s_waitcnt vmcnt(4)" ::: "memory");
    else            asm volatile("s_waitcnt vmcnt(0)" ::: "memory");
    __builtin_amdgcn_s_barrier();

    const char* Ab = (const char*)(As + cur * 4096);
    const char* Bb = (const char*)(Bs + cur * 4096);
    half8 af[2][2], bf[2][2];
#pragma unroll
    for (int kc = 0; kc < 2; ++kc) {
#pragma unroll
      for (int mi = 0; mi < 2; ++mi) {
        int row = wr * 32 + mi * 16 + r16;
        af[mi][kc] = *(const half8*)(Ab + row * 128 +
                     (((kc << 6) + (kh << 4)) ^ ((row & 7) << 4)));
      }
#pragma unroll
      for (int ni = 0; ni < 2; ++ni) {
        int row = wc * 32 + ni * 16 + r16;
        bf[ni][kc] = *(const half8*)(Bb + row * 128 +
                     (((kc << 6) + (kh << 4)) ^ ((row & 7) << 4)));
      }
    }
#pragma unroll
    for (int kc = 0; kc < 2; ++kc)
#pragma unroll
      for (int mi = 0; mi < 2; ++mi)
#pragma unroll
        for (int ni = 0; ni < 2; ++ni)
          acc[mi][ni] = __builtin_amdgcn_mfma_f32_16x16x32_f16(
              af[mi][kc], bf[ni][kc], acc[mi][ni], 0, 0, 0);
    cur = cur == 2 ? 0 : cur + 1;
  }

#pragma unroll
  for (int mi = 0; mi < 2; ++mi)
#pragma unroll
    for (int ni = 0; ni < 2; ++ni) {
      int row = m0 + wr * 32 + mi * 16 + kh * 4;    // C/D: row=(l>>4)*4+rr
      int col = n0 + wc * 32 + ni * 16 + r16;       //      col=l&15
      float bb = (col < Nreal) ? bias[col] : 0.f;
#pragma unroll
      for (int rr = 0; rr < 4; ++rr) {
        float x = acc[mi][ni][rr] + bb;
        if (RELU) x = fmaxf(x, 0.f);
        if (o16) o16[(size_t)(row + rr) * Npad + col] = (_Float16)x;
        else     o32[(size_t)(row + rr) * Npad + col] = x;
      }
    }
}

// ---- combine split-K partials + bias + relu, emit fp16 (L1 only) ----------
__global__ void combine_sk(const float* __restrict__ part, int SK, int M, int Npad,
                           const float* __restrict__ bias, int Nreal,
                           _Float16* __restrict__ o16) {
  int i4 = (blockIdx.x * 256 + threadIdx.x) * 4;
  int total = M * Npad;
  if (i4 >= total) return;
  f32x4 s = (f32x4){0.f, 0.f, 0.f, 0.f};
  for (int zz = 0; zz < SK; ++zz)
    s += *(const f32x4*)&part[(size_t)zz * total + i4];
  int n = i4 & (Npad - 1);
  half4 v;
#pragma unroll
  for (int e = 0; e < 4; ++e) {
    float x = s[e] + ((n + e) < Nreal ? bias[n + e] : 0.f);
    v[e] = (_Float16)fmaxf(x, 0.f);
  }
  *(half4*)(o16 + i4) = v;
}

// ---- cosine over E [512][NOP] fp32 ----------------------------------------
__global__ void cosine_E(const float* __restrict__ E, float* __restrict__ out) {
  const int b = blockIdx.x, t = threadIdx.x;
  float d = 0.f, s1 = 0.f, s2 = 0.f;
  for (int c = t; c < NOP; c += 256) {
    float e1 = E[(size_t)b * NOP + c];
    float e2 = E[(size_t)(b + BATCH) * NOP + c];
    d += e1 * e2; s1 += e1 * e1; s2 += e2 * e2;
  }
  for (int off = 32; off > 0; off >>= 1) {
    d  += __shfl_down(d, off, 64);
    s1 += __shfl_down(s1, off, 64);
    s2 += __shfl_down(s2, off, 64);
  }
  __shared__ float rd[4], r1[4], r2[4];
  int wd = t >> 6, lane = t & 63;
  if (lane == 0) { rd[wd] = d; r1[wd] = s1; r2[wd] = s2; }
  __syncthreads();
  if (t == 0) {
    float D  = rd[0] + rd[1] + rd[2] + rd[3];
    float S1 = r1[0] + r1[1] + r1[2] + r1[3];
    float S2 = r2[0] + r2[1] + r2[2] + r2[3];
    float n1 = fmaxf(sqrtf(S1), 1e-6f);
    float n2 = fmaxf(sqrtf(S2), 1e-6f);
    out[b] = D / (n1 * n2);
  }
}

extern "C" void kernel_launch(void* const* d_in, const int* in_sizes, int n_in,
                              void* d_out, int out_size, void* d_ws, size_t ws_size,
                              hipStream_t stream) {
  const float* mz1 = (const float*)d_in[0];
  const float* it1 = (const float*)d_in[1];
  const float* mz2 = (const float*)d_in[2];
  const float* it2 = (const float*)d_in[3];
  const float* Wg  = (const float*)d_in[4];
  const float* bg  = (const float*)d_in[5];
  const float* W1  = (const float*)d_in[6];
  const float* b1  = (const float*)d_in[7];
  const float* W2  = (const float*)d_in[8];
  const float* b2  = (const float*)d_in[9];
  const float* W3  = (const float*)d_in[10];
  const float* b3  = (const float*)d_in[11];
  const float* Wo  = (const float*)d_in[12];
  const float* bo  = (const float*)d_in[13];
  float* out = (float*)d_out;

  char* ws = (char*)d_ws;
  size_t off = 0;
  auto take = [&](size_t bytes) {
    size_t o = off; off += (bytes + 255) & ~(size_t)255; return o;
  };
  float*    part = (float*)   (ws + take((size_t)8 * ROWS * NP * 4));  // 16MB
  _Float16* h16  = (_Float16*)(ws + take((size_t)ROWS * K1P * 2));
  _Float16* W1t  = (_Float16*)(ws + take((size_t)NP * K1P * 2));
  _Float16* W2t  = (_Float16*)(ws + take((size_t)NP * NP * 2));
  _Float16* W3t  = (_Float16*)(ws + take((size_t)NP * NP * 2));
  _Float16* Wot  = (_Float16*)(ws + take((size_t)NOP * NP * 2));
  _Float16* y1   = (_Float16*)(ws + take((size_t)ROWS * NP * 2));
  _Float16* y2   = (_Float16*)(ws + take((size_t)ROWS * NP * 2));
  _Float16* y3   = (_Float16*)(ws + take((size_t)ROWS * NP * 2));
  float*    E    = (float*)   (ws + take((size_t)ROWS * NOP * 4));

  // 1) binning + grouped linear + all weight transposes, ONE dispatch
  prep4<<<1824, 256, 0, stream>>>(mz1, it1, mz2, it2, Wg, bg, h16,
                                  W1, W1t, W2, W2t, W3, W3t, Wo, Wot);

  // 2) L1: split-K=8 GEMM + combine (K=10048)
  gemm_sk<true><<<512, 256, 0, stream>>>(
      h16, K1P, W1t, K1P, part, ROWS, NP, K1P / 64, 20);
  combine_sk<<<(ROWS * NP) / 1024, 256, 0, stream>>>(part, 8, ROWS, NP, b1, 1000, y1);

  // 3) L2/L3/Lo: full-K GEMMs with fused bias(+relu) epilogues
  gemm_full<1><<<dim3(NP / 64, ROWS / 64), 256, 0, stream>>>(
      y1, W2t, b2, 1000, NP, y2, nullptr);
  gemm_full<1><<<dim3(NP / 64, ROWS / 64), 256, 0, stream>>>(
      y2, W3t, b3, 1000, NP, y3, nullptr);
  gemm_full<0><<<dim3(NOP / 64, ROWS / 64), 256, 0, stream>>>(
      y3, Wot, bo, 500, NOP, nullptr, E);

  // 4) cosine
  cosine_E<<<BATCH, 256, 0, stream>>>(E, out);
}

// Round 12
// 88.089 us; speedup vs baseline: 2.5439x; 1.0133x over previous
//
#include <hip/hip_runtime.h>
#include <hip/hip_fp16.h>

using half8  = __attribute__((ext_vector_type(8))) _Float16;
using half4  = __attribute__((ext_vector_type(4))) _Float16;
using f32x4  = __attribute__((ext_vector_type(4))) float;

#define GROUPS      3333
#define BINNER_OUT  9999
#define BATCH       256
#define ROWS        512          // 2 spectra x 256
#define PEAKS       512
#define K1          9999
#define K1P         10048        // padded to mult of 64 (157*64)
#define NP          1024         // hidden 1000 padded
#define NOP         512          // out 500 padded
#define HALFK       5024         // K1P/2, per-bin-block column range

// ---- async global->LDS, 16B per lane (dest = uniform base + lane*16) ------
__device__ __forceinline__ void gl_lds16(const void* g, void* l) {
  __builtin_amdgcn_global_load_lds(
      (const __attribute__((address_space(1))) void*)g,
      (__attribute__((address_space(3))) void*)l, 16, 0, 0);
}

// ---- native LDS fp32 atomic add (relaxed, workgroup scope -> ds_add_f32) --
__device__ __forceinline__ void hs_add(float* p, float v) {
  __hip_atomic_fetch_add(p, v, __ATOMIC_RELAXED, __HIP_MEMORY_SCOPE_WORKGROUP);
}

// ---- prep5: binning (1024 blocks, half-row each) + transposes (800) -------
// Transpose path now stages tiles via global_load_lds (guaranteed issue,
// linear LDS dest); OOB cells source-clamped + zeroed by read predicate.
__global__ __launch_bounds__(256) void prep5(
    const float* __restrict__ mz1, const float* __restrict__ it1,
    const float* __restrict__ mz2, const float* __restrict__ it2,
    const float* __restrict__ Wg,  const float* __restrict__ bg,
    _Float16* __restrict__ h16,
    const float* __restrict__ W1, _Float16* __restrict__ W1t,
    const float* __restrict__ W2, _Float16* __restrict__ W2t,
    const float* __restrict__ W3, _Float16* __restrict__ W3t,
    const float* __restrict__ Wo, _Float16* __restrict__ Wot) {
  __shared__ __align__(16) char smem[HALFK * 4];    // 20096 B
  const int t = threadIdx.x;
  const int blk = blockIdx.x;

  if (blk < 1024) {
    // ---------------- binning + grouped linear (half row) ----------------
    float* hs = (float*)smem;                       // 5024 floats
    const int row = blk >> 1, half = blk & 1;
    const int base = half * HALFK;
    const int s = row >> 8, b = row & 255;

    for (int k = t * 4; k < HALFK; k += 1024)
      *(f32x4*)&hs[k] = (f32x4){0.f, 0.f, 0.f, 0.f};
    __syncthreads();

    const float* mz = (s ? mz2 : mz1) + (size_t)b * PEAKS;
    const float* it = (s ? it2 : it1) + (size_t)b * PEAKS;

    float m[2], v[2], w[2][3]; int c0[2]; bool keep[2];
#pragma unroll
    for (int q = 0; q < 2; ++q) { m[q] = mz[t + q * 256]; v[q] = it[t + q * 256]; }
#pragma unroll
    for (int q = 0; q < 2; ++q) {
      bool val = (m[q] >= 0.0f && m[q] < 1000.0f);
      int bin = val ? (int)floorf(m[q] / 0.01f) : 0;  // IEEE div+floor = jnp
      bin = bin < 0 ? 0 : (bin > 99999 ? 99999 : bin);
      keep[q] = val && (bin < GROUPS * 30);       // ref drops bins 99990..99999
      int binL = bin < GROUPS * 30 ? bin : GROUPS * 30 - 1;  // safe gather idx
      const float* wp = Wg + (size_t)binL * 3;    // Wg[g][i][o] flat
      w[q][0] = wp[0]; w[q][1] = wp[1]; w[q][2] = wp[2];
      c0[q] = (bin / 30) * 3;
    }
#pragma unroll
    for (int q = 0; q < 2; ++q)
      if (keep[q]) {
#pragma unroll
        for (int o = 0; o < 3; ++o) {
          int c = c0[q] + o;
          if (c >= base && c < base + HALFK)
            hs_add(&hs[c - base], v[q] * w[q][o]);
        }
      }
    __syncthreads();

    _Float16* dst = h16 + (size_t)row * K1P + base;
    for (int k0 = t * 8; k0 < HALFK; k0 += 2048) {
      half8 vv;
#pragma unroll
      for (int j = 0; j < 8; ++j) {
        int c = base + k0 + j;
        float x = hs[k0 + j] + (c < BINNER_OUT ? bg[c] : 0.f);
        vv[j] = (_Float16)x;
      }
      *(half8*)(dst + k0) = vv;
    }
  } else {
    // ---- weight transpose+convert, 4 x (64x64) tiles, gl_lds16 staging ----
    // out[n*Kpad + k] = fp16(W[k*N + n]), zero-padded.
    float* tf = (float*)smem;                       // linear [64][64] = 16 KB
    int bid = blk - 1024;
    const float* W; _Float16* outp; int K, N, Kpad, g, in, ktiles;
    if (bid < 640)       { W = W1; outp = W1t; K = K1;   N = 1000; Kpad = K1P;
                           ktiles = 157; g = bid % 40; in = bid / 40; }
    else if (bid < 704)  { bid -= 640; W = W2; outp = W2t; K = 1000; N = 1000;
                           Kpad = NP; ktiles = 16; g = bid & 3; in = bid >> 2; }
    else if (bid < 768)  { bid -= 704; W = W3; outp = W3t; K = 1000; N = 1000;
                           Kpad = NP; ktiles = 16; g = bid & 3; in = bid >> 2; }
    else                 { bid -= 768; W = Wo; outp = Wot; K = 1000; N = 500;
                           Kpad = NP; ktiles = 16; g = bid & 3; in = bid >> 2; }
    const int ntile = min(4, ktiles - g * 4);
    const int k0base = g * 256, n0 = in * 64;
    const int l = t & 63, wv = t >> 6;
    const int r = t >> 2, cc = (t & 3) * 16;        // read: n-row r, k-chunk cc
    const bool rok = (n0 + r < N);

    // staging geometry: inst (wv,j), lane l -> tile row (wv*4+j)*4 + l/16,
    // col (l&15)*4 (4 consecutive floats = 16B); dest = base + (wv*4+j)*1024
    const int srow_l = l >> 4, scol = (l & 15) * 4;
    const int gnc = n0 + scol;
    const int gn = (gnc < N) ? gnc : 0;             // clamp col (zeroed later)

    for (int i = 0; i < ntile; ++i) {
      const int k0 = k0base + i * 64;
#pragma unroll
      for (int j = 0; j < 4; ++j) {
        int gk = k0 + (wv * 4 + j) * 4 + srow_l;
        if (gk >= K) gk = K - 1;                    // clamp row (zeroed later)
        gl_lds16(W + (size_t)gk * N + gn, smem + (wv * 4 + j) * 1024);
      }
      __syncthreads();                              // drains vmcnt -> LDS ready

#pragma unroll
      for (int h = 0; h < 2; ++h) {
        half8 v;
#pragma unroll
        for (int e = 0; e < 8; ++e) {
          int kk = cc + h * 8 + e;
          float x = (rok && (k0 + kk) < K) ? tf[kk * 64 + r] : 0.f;
          v[e] = (_Float16)x;
        }
        *(half8*)(outp + (size_t)(n0 + r) * Kpad + k0 + cc + h * 8) = v;
      }
      __syncthreads();                              // LDS free for next tile
    }
  }
}

// ---- split-K fp16 MFMA GEMM (L1 only), 3-deep counted-vmcnt pipeline ------
template <bool SWZ>
__global__ __launch_bounds__(256) void gemm_sk(
    const _Float16* __restrict__ A, int lda,
    const _Float16* __restrict__ Bt, int ldb,
    float* __restrict__ part, int M, int Npad, int ksteps_total, int kspc) {
  __shared__ __align__(16) _Float16 As[3 * 4096];   // 3 x 64x64  = 24 KB
  __shared__ __align__(16) _Float16 Bs[3 * 8192];   // 3 x 128x64 = 48 KB

  int bx, by, bz;
  if (SWZ) {   // 512 blocks = 8x8x8; each XCD owns a 2(bx) x 4(by) region
    int bid = blockIdx.x;
    int xcd = bid & 7, i = bid >> 3;
    bz = i >> 3;
    int j = i & 7;
    bx = (xcd & 3) * 2 + (j & 1);
    by = (xcd >> 2) * 4 + (j >> 1);
  } else {
    bx = blockIdx.x; by = blockIdx.y; bz = blockIdx.z;
  }

  const int t = threadIdx.x, lane = t & 63, wid = t >> 6;
  const int m0 = by * 64, n0 = bx * 128;
  const int s0 = bz * kspc;
  const int s1 = min(s0 + kspc, ksteps_total);

  const int wr = wid >> 1, wc = wid & 1;            // 2x2 waves, 32x64 each
  const int r16 = lane & 15, kh = lane >> 4;
  const int lr  = lane >> 3;
  const int lkc = ((lane & 7) ^ lr) * 8;
  const _Float16* AgL = A  + (size_t)(m0 + wid * 16 + lr) * lda + lkc;
  const _Float16* BgL = Bt + (size_t)(n0 + wid * 32 + lr) * ldb + lkc;

  f32x4 acc[2][4] = {};
  auto STAGE = [&](int s, int buf) {
    const size_t ko = (size_t)s * 64;
    _Float16* ab = As + buf * 4096 + wid * 1024;
    _Float16* bb = Bs + buf * 8192 + wid * 2048;
    gl_lds16(AgL + ko,                     ab);
    gl_lds16(AgL + ko + (size_t) 8 * lda,  ab + 512);
    gl_lds16(BgL + ko,                     bb);
    gl_lds16(BgL + ko + (size_t) 8 * ldb,  bb + 512);
    gl_lds16(BgL + ko + (size_t)16 * ldb,  bb + 1024);
    gl_lds16(BgL + ko + (size_t)24 * ldb,  bb + 1536);
  };

  if (s0 < s1)     STAGE(s0, 0);
  if (s0 + 1 < s1) STAGE(s0 + 1, 1);

  int cur = 0;
  for (int s = s0; s < s1; ++s) {
    __builtin_amdgcn_s_barrier();
    const bool more2 = (s + 2 < s1), more1 = (s + 1 < s1);
    if (more2) STAGE(s + 2, cur == 0 ? 2 : (cur == 1 ? 0 : 1));
    if (more2)      asm volatile("s_waitcnt vmcnt(12)" ::: "memory");
    else if (more1) asm volatile("s_waitcnt vmcnt(6)"  ::: "memory");
    else            asm volatile("s_waitcnt vmcnt(0)"  ::: "memory");
    __builtin_amdgcn_s_barrier();

    const char* Ab = (const char*)(As + cur * 4096);
    const char* Bb = (const char*)(Bs + cur * 8192);
    half8 af[2][2], bf[4][2];
#pragma unroll
    for (int kc = 0; kc < 2; ++kc) {
#pragma unroll
      for (int mi = 0; mi < 2; ++mi) {
        int row = wr * 32 + mi * 16 + r16;
        af[mi][kc] = *(const half8*)(Ab + row * 128 +
                     (((kc << 6) + (kh << 4)) ^ ((row & 7) << 4)));
      }
#pragma unroll
      for (int ni = 0; ni < 4; ++ni) {
        int row = wc * 64 + ni * 16 + r16;
        bf[ni][kc] = *(const half8*)(Bb + row * 128 +
                     (((kc << 6) + (kh << 4)) ^ ((row & 7) << 4)));
      }
    }
#pragma unroll
    for (int kc = 0; kc < 2; ++kc)
#pragma unroll
      for (int mi = 0; mi < 2; ++mi)
#pragma unroll
        for (int ni = 0; ni < 4; ++ni)
          acc[mi][ni] = __builtin_amdgcn_mfma_f32_16x16x32_f16(
              af[mi][kc], bf[ni][kc], acc[mi][ni], 0, 0, 0);
    cur = cur == 2 ? 0 : cur + 1;
  }

  float* P = part + (size_t)bz * M * Npad;
#pragma unroll
  for (int mi = 0; mi < 2; ++mi)
#pragma unroll
    for (int ni = 0; ni < 4; ++ni) {
      int row = m0 + wr * 32 + mi * 16 + kh * 4;    // C/D: row=(l>>4)*4+rr
      int col = n0 + wc * 64 + ni * 16 + r16;       //      col=l&15
#pragma unroll
      for (int rr = 0; rr < 4; ++rr)
        P[(size_t)(row + rr) * Npad + col] = acc[mi][ni][rr];
    }
}

// ---- full-K fp16 MFMA GEMM (L2/L3/Lo): 64x64 tile, fused bias(+relu) ------
template <int RELU>
__global__ __launch_bounds__(256) void gemm_full(
    const _Float16* __restrict__ A,
    const _Float16* __restrict__ Bt,
    const float* __restrict__ bias, int Nreal, int Npad,
    _Float16* __restrict__ o16, float* __restrict__ o32) {
  __shared__ __align__(16) _Float16 As[3 * 4096];   // 3 x 64x64 = 24 KB
  __shared__ __align__(16) _Float16 Bs[3 * 4096];   // 3 x 64x64 = 24 KB

  const int bx = blockIdx.x, by = blockIdx.y;
  const int t = threadIdx.x, lane = t & 63, wid = t >> 6;
  const int m0 = by * 64, n0 = bx * 64;
  const int wr = wid >> 1, wc = wid & 1;            // 2x2 waves, 32x32 each
  const int r16 = lane & 15, kh = lane >> 4;
  const int lr  = lane >> 3;
  const int lkc = ((lane & 7) ^ lr) * 8;
  const _Float16* AgL = A  + (size_t)(m0 + wid * 16 + lr) * NP + lkc;
  const _Float16* BgL = Bt + (size_t)(n0 + wid * 16 + lr) * NP + lkc;

  f32x4 acc[2][2] = {};
  auto STAGE = [&](int s, int buf) {                // 4 VMEM insts / thread
    const size_t ko = (size_t)s * 64;
    _Float16* ab = As + buf * 4096 + wid * 1024;
    _Float16* bb = Bs + buf * 4096 + wid * 1024;
    gl_lds16(AgL + ko,                    ab);
    gl_lds16(AgL + ko + (size_t)8 * NP,   ab + 512);
    gl_lds16(BgL + ko,                    bb);
    gl_lds16(BgL + ko + (size_t)8 * NP,   bb + 512);
  };

  STAGE(0, 0);
  STAGE(1, 1);

  int cur = 0;
  for (int s = 0; s < 16; ++s) {
    __builtin_amdgcn_s_barrier();
    const bool more2 = (s + 2 < 16), more1 = (s + 1 < 16);
    if (more2) STAGE(s + 2, cur == 0 ? 2 : (cur == 1 ? 0 : 1));
    if (more2)      asm volatile("s_waitcnt vmcnt(8)" ::: "memory");
    else if (more1) asm volatile("s_waitcnt vmcnt(4)" ::: "memory");
    else            asm volatile("s_waitcnt vmcnt(0)" ::: "memory");
    __builtin_amdgcn_s_barrier();

    const char* Ab = (const char*)(As + cur * 4096);
    const char* Bb = (const char*)(Bs + cur * 4096);
    half8 af[2][2], bf[2][2];
#pragma unroll
    for (int kc = 0; kc < 2; ++kc) {
#pragma unroll
      for (int mi = 0; mi < 2; ++mi) {
        int row = wr * 32 + mi * 16 + r16;
        af[mi][kc] = *(const half8*)(Ab + row * 128 +
                     (((kc << 6) + (kh << 4)) ^ ((row & 7) << 4)));
      }
#pragma unroll
      for (int ni = 0; ni < 2; ++ni) {
        int row = wc * 32 + ni * 16 + r16;
        bf[ni][kc] = *(const half8*)(Bb + row * 128 +
                     (((kc << 6) + (kh << 4)) ^ ((row & 7) << 4)));
      }
    }
#pragma unroll
    for (int kc = 0; kc < 2; ++kc)
#pragma unroll
      for (int mi = 0; mi < 2; ++mi)
#pragma unroll
        for (int ni = 0; ni < 2; ++ni)
          acc[mi][ni] = __builtin_amdgcn_mfma_f32_16x16x32_f16(
              af[mi][kc], bf[ni][kc], acc[mi][ni], 0, 0, 0);
    cur = cur == 2 ? 0 : cur + 1;
  }

#pragma unroll
  for (int mi = 0; mi < 2; ++mi)
#pragma unroll
    for (int ni = 0; ni < 2; ++ni) {
      int row = m0 + wr * 32 + mi * 16 + kh * 4;    // C/D: row=(l>>4)*4+rr
      int col = n0 + wc * 32 + ni * 16 + r16;       //      col=l&15
      float bb = (col < Nreal) ? bias[col] : 0.f;
#pragma unroll
      for (int rr = 0; rr < 4; ++rr) {
        float x = acc[mi][ni][rr] + bb;
        if (RELU) x = fmaxf(x, 0.f);
        if (o16) o16[(size_t)(row + rr) * Npad + col] = (_Float16)x;
        else     o32[(size_t)(row + rr) * Npad + col] = x;
      }
    }
}

// ---- combine split-K partials + bias + relu, emit fp16 (L1 only) ----------
__global__ void combine_sk(const float* __restrict__ part, int SK, int M, int Npad,
                           const float* __restrict__ bias, int Nreal,
                           _Float16* __restrict__ o16) {
  int i4 = (blockIdx.x * 256 + threadIdx.x) * 4;
  int total = M * Npad;
  if (i4 >= total) return;
  f32x4 s = (f32x4){0.f, 0.f, 0.f, 0.f};
  for (int zz = 0; zz < SK; ++zz)
    s += *(const f32x4*)&part[(size_t)zz * total + i4];
  int n = i4 & (Npad - 1);
  half4 v;
#pragma unroll
  for (int e = 0; e < 4; ++e) {
    float x = s[e] + ((n + e) < Nreal ? bias[n + e] : 0.f);
    v[e] = (_Float16)fmaxf(x, 0.f);
  }
  *(half4*)(o16 + i4) = v;
}

// ---- cosine over E [512][NOP] fp32 ----------------------------------------
__global__ void cosine_E(const float* __restrict__ E, float* __restrict__ out) {
  const int b = blockIdx.x, t = threadIdx.x;
  float d = 0.f, s1 = 0.f, s2 = 0.f;
  for (int c = t; c < NOP; c += 256) {
    float e1 = E[(size_t)b * NOP + c];
    float e2 = E[(size_t)(b + BATCH) * NOP + c];
    d += e1 * e2; s1 += e1 * e1; s2 += e2 * e2;
  }
  for (int off = 32; off > 0; off >>= 1) {
    d  += __shfl_down(d, off, 64);
    s1 += __shfl_down(s1, off, 64);
    s2 += __shfl_down(s2, off, 64);
  }
  __shared__ float rd[4], r1[4], r2[4];
  int wd = t >> 6, lane = t & 63;
  if (lane == 0) { rd[wd] = d; r1[wd] = s1; r2[wd] = s2; }
  __syncthreads();
  if (t == 0) {
    float D  = rd[0] + rd[1] + rd[2] + rd[3];
    float S1 = r1[0] + r1[1] + r1[2] + r1[3];
    float S2 = r2[0] + r2[1] + r2[2] + r2[3];
    float n1 = fmaxf(sqrtf(S1), 1e-6f);
    float n2 = fmaxf(sqrtf(S2), 1e-6f);
    out[b] = D / (n1 * n2);
  }
}

extern "C" void kernel_launch(void* const* d_in, const int* in_sizes, int n_in,
                              void* d_out, int out_size, void* d_ws, size_t ws_size,
                              hipStream_t stream) {
  const float* mz1 = (const float*)d_in[0];
  const float* it1 = (const float*)d_in[1];
  const float* mz2 = (const float*)d_in[2];
  const float* it2 = (const float*)d_in[3];
  const float* Wg  = (const float*)d_in[4];
  const float* bg  = (const float*)d_in[5];
  const float* W1  = (const float*)d_in[6];
  const float* b1  = (const float*)d_in[7];
  const float* W2  = (const float*)d_in[8];
  const float* b2  = (const float*)d_in[9];
  const float* W3  = (const float*)d_in[10];
  const float* b3  = (const float*)d_in[11];
  const float* Wo  = (const float*)d_in[12];
  const float* bo  = (const float*)d_in[13];
  float* out = (float*)d_out;

  char* ws = (char*)d_ws;
  size_t off = 0;
  auto take = [&](size_t bytes) {
    size_t o = off; off += (bytes + 255) & ~(size_t)255; return o;
  };
  float*    part = (float*)   (ws + take((size_t)8 * ROWS * NP * 4));  // 16MB
  _Float16* h16  = (_Float16*)(ws + take((size_t)ROWS * K1P * 2));
  _Float16* W1t  = (_Float16*)(ws + take((size_t)NP * K1P * 2));
  _Float16* W2t  = (_Float16*)(ws + take((size_t)NP * NP * 2));
  _Float16* W3t  = (_Float16*)(ws + take((size_t)NP * NP * 2));
  _Float16* Wot  = (_Float16*)(ws + take((size_t)NOP * NP * 2));
  _Float16* y1   = (_Float16*)(ws + take((size_t)ROWS * NP * 2));
  _Float16* y2   = (_Float16*)(ws + take((size_t)ROWS * NP * 2));
  _Float16* y3   = (_Float16*)(ws + take((size_t)ROWS * NP * 2));
  float*    E    = (float*)   (ws + take((size_t)ROWS * NOP * 4));

  // 1) binning + grouped linear + all weight transposes, ONE dispatch
  prep5<<<1824, 256, 0, stream>>>(mz1, it1, mz2, it2, Wg, bg, h16,
                                  W1, W1t, W2, W2t, W3, W3t, Wo, Wot);

  // 2) L1: split-K=8 GEMM + combine (K=10048)
  gemm_sk<true><<<512, 256, 0, stream>>>(
      h16, K1P, W1t, K1P, part, ROWS, NP, K1P / 64, 20);
  combine_sk<<<(ROWS * NP) / 1024, 256, 0, stream>>>(part, 8, ROWS, NP, b1, 1000, y1);

  // 3) L2/L3/Lo: full-K GEMMs with fused bias(+relu) epilogues
  gemm_full<1><<<dim3(NP / 64, ROWS / 64), 256, 0, stream>>>(
      y1, W2t, b2, 1000, NP, y2, nullptr);
  gemm_full<1><<<dim3(NP / 64, ROWS / 64), 256, 0, stream>>>(
      y2, W3t, b3, 1000, NP, y3, nullptr);
  gemm_full<0><<<dim3(NOP / 64, ROWS / 64), 256, 0, stream>>>(
      y3, Wot, bo, 500, NOP, nullptr, E);

  // 4) cosine
  cosine_E<<<BATCH, 256, 0, stream>>>(E, out);
}